// Round 4
// baseline (465.378 us; speedup 1.0000x reference)
//
#include <hip/hip_runtime.h>

#define B_      64
#define C_      512
#define NNODE   128
#define NEDGE   1024
#define NLAYERS 8
#define EPS_    1e-5f

typedef __attribute__((ext_vector_type(8))) short bf16x8;
typedef __attribute__((ext_vector_type(4))) float f32x4;

__device__ __forceinline__ ushort f2b(float x) {
    unsigned u = __builtin_bit_cast(unsigned, x);
    unsigned r = (u + 0x7fffu + ((u >> 16) & 1u)) >> 16;
    return (ushort)r;
}
__device__ __forceinline__ float b2f(ushort h) {
    unsigned u = ((unsigned)h) << 16;
    return __builtin_bit_cast(float, u);
}

// ---------------- graph prep ----------------

__global__ void zero_k(float* __restrict__ p, int n) {
    int i = blockIdx.x * 256 + threadIdx.x;
    if (i < n) p[i] = 0.0f;
}

__global__ void count_deg_k(const int* __restrict__ ei, float* __restrict__ deg) {
    int e = blockIdx.x * 256 + threadIdx.x;
    if (e < NEDGE) atomicAdd(&deg[ei[NEDGE + e]], 1.0f);
}

__global__ void dinv_k(float* __restrict__ deg) {
    int n = threadIdx.x;
    deg[n] = 1.0f / sqrtf(deg[n] + 1.0f);
}

__global__ void build_A_k(const int* __restrict__ ei, const float* __restrict__ dinv,
                          float* __restrict__ A) {
    int e = blockIdx.x * 256 + threadIdx.x;
    if (e < NEDGE) {
        int s = ei[e];
        int d = ei[NEDGE + e];
        atomicAdd(&A[d * NNODE + s], dinv[s] * dinv[d]);
    } else if (e < NEDGE + NNODE) {
        int n = e - NEDGE;
        atomicAdd(&A[n * NNODE + n], dinv[n] * dinv[n]);
    }
}

__global__ void splitA_k(const float* __restrict__ A, ushort* __restrict__ Ah,
                         ushort* __restrict__ Al) {
    int i = blockIdx.x * 256 + threadIdx.x;
    if (i < NNODE * NNODE) {
        float v = A[i];
        ushort h = f2b(v);
        Ah[i] = h;
        Al[i] = f2b(v - b2f(h));
    }
}

// ---------------- W transpose + split: WT[l][n][k] = W[l][k][n] ----------------
__global__ __launch_bounds__(256) void wprep_k(const float* __restrict__ W,
                                               ushort* __restrict__ WTh,
                                               ushort* __restrict__ WTl) {
    __shared__ float tl[64][68];
    const int t = threadIdx.x;
    const int n0 = blockIdx.x * 64, k0 = blockIdx.y * 64, l = blockIdx.z;
    const float* Wl = W + (size_t)l * C_ * C_;
    {
        int kk = t >> 2, nc = (t & 3) * 16;
        const float* src = Wl + (size_t)(k0 + kk) * C_ + n0 + nc;
#pragma unroll
        for (int g = 0; g < 4; ++g)
            *(float4*)&tl[kk][nc + g * 4] = *(const float4*)(src + g * 4);
    }
    __syncthreads();
    {
        int nn = t >> 2, kc = (t & 3) * 16;
        ushort h[16], lo[16];
#pragma unroll
        for (int j = 0; j < 16; ++j) {
            float v = tl[kc + j][nn];
            h[j] = f2b(v);
            lo[j] = f2b(v - b2f(h[j]));
        }
        size_t o = ((size_t)l * C_ + n0 + nn) * C_ + k0 + kc;
        *(int4*)&WTh[o] = *(int4*)&h[0];
        *(int4*)&WTh[o + 8] = *(int4*)&h[8];
        *(int4*)&WTl[o] = *(int4*)&lo[0];
        *(int4*)&WTl[o + 8] = *(int4*)&lo[8];
    }
}

// ---------------- fused pool + pos + split -> x0 ----------------
// 32 channels/block, grid (16, 64). Lane-contiguous loads: wave reads 1KB/instr.
__global__ __launch_bounds__(256) void pool_x_k(const float* __restrict__ rgb,
                                                const float* __restrict__ ir,
                                                const float* __restrict__ pos,
                                                ushort* __restrict__ xh,
                                                ushort* __restrict__ xl) {
    __shared__ float lds[32][130];
    const int t = threadIdx.x, l = t & 63, wv = t >> 6;
    const int c0 = blockIdx.x * 32, b = blockIdx.y;

    for (int i = 0; i < 16; ++i) {
        int p = wv * 16 + i;                 // 0..63
        int src = p >> 5, cc = p & 31;       // src uniform per wave
        const float* base = (src ? ir : rgb) + ((size_t)(b * C_ + c0 + cc)) * 1024;
        float s[4];
#pragma unroll
        for (int g = 0; g < 4; ++g) {
            float4 v = *(const float4*)(base + g * 256 + l * 4);
            s[g] = v.x + v.y + v.z + v.w;
        }
#pragma unroll
        for (int g = 0; g < 4; ++g) {
            s[g] += __shfl_xor(s[g], 8);
            s[g] += __shfl_xor(s[g], 16);
        }
        if (((l >> 3) & 3) == 0) {           // j==0 rows: lanes 0..7, 32..39
            int ha = l & 7, hi = l >> 5;
#pragma unroll
            for (int g = 0; g < 4; ++g)
                lds[cc][src * 64 + (2 * g + hi) * 8 + ha] = s[g] * 0.0625f;
        }
    }
    __syncthreads();

    const int n = t >> 1, cb = (t & 1) * 16;
    float v[16];
#pragma unroll
    for (int j = 0; j < 16; j += 4) {
        float4 pv = *(const float4*)&pos[(size_t)n * C_ + c0 + cb + j];
        v[j + 0] = lds[cb + j + 0][n] + pv.x;
        v[j + 1] = lds[cb + j + 1][n] + pv.y;
        v[j + 2] = lds[cb + j + 2][n] + pv.z;
        v[j + 3] = lds[cb + j + 3][n] + pv.w;
    }
    ushort hs[16], ls[16];
#pragma unroll
    for (int j = 0; j < 16; ++j) {
        hs[j] = f2b(v[j]);
        ls[j] = f2b(v[j] - b2f(hs[j]));
    }
    size_t o = ((size_t)(b * NNODE + n)) * C_ + c0 + cb;
    *(int4*)&xh[o] = *(int4*)&hs[0];
    *(int4*)&xh[o + 8] = *(int4*)&hs[8];
    *(int4*)&xl[o] = *(int4*)&ls[0];
    *(int4*)&xl[o + 8] = *(int4*)&ls[8];
}

// ---------------- fused layer: x' = relu(A @ (x @ W) + bias) ----------------
// grid (4 n-tiles of 128, 64 b), 4 waves, wave tile 64x64.
// Stage-1 operands read DIRECTLY from global (L2-resident) - no LDS, no barriers.
__global__ __launch_bounds__(256) void gemm_fused_k(
    const ushort* __restrict__ Xh, const ushort* __restrict__ Xl,
    const ushort* __restrict__ Wh, const ushort* __restrict__ Wl,
    const ushort* __restrict__ Agh, const ushort* __restrict__ Agl,
    const float* __restrict__ bias,
    ushort* __restrict__ Yh, ushort* __restrict__ Yl) {
    __shared__ __align__(16) char smem[65536];
    ushort* sPh = (ushort*)smem;                 // [128 n][128 m] granule-swizzled
    ushort* sPl = (ushort*)(smem + 32768);
    float*  sT  = (float*)smem;                  // [128][68] half-tile

    const int t = threadIdx.x, lane = t & 63;
    const int wv = t >> 6, wm = wv >> 1, wn = wv & 1;
    const int lr = lane & 15, lq = lane >> 4;
    const int bn = blockIdx.x * 128, b = blockIdx.y;

    const ushort* xh = Xh + (size_t)b * NNODE * C_;
    const ushort* xl = Xl + (size_t)b * NNODE * C_;

    size_t aoff[4], boff[4];
#pragma unroll
    for (int mf = 0; mf < 4; ++mf)
        aoff[mf] = (size_t)(wm * 64 + mf * 16 + lr) * C_ + lq * 8;
#pragma unroll
    for (int nf = 0; nf < 4; ++nf)
        boff[nf] = (size_t)(bn + wn * 64 + nf * 16 + lr) * C_ + lq * 8;

    f32x4 acc[4][4];
#pragma unroll
    for (int i = 0; i < 4; ++i)
#pragma unroll
        for (int j = 0; j < 4; ++j) acc[i][j] = (f32x4){0.f, 0.f, 0.f, 0.f};

    float bv[4];
#pragma unroll
    for (int nf = 0; nf < 4; ++nf) bv[nf] = bias[bn + wn * 64 + nf * 16 + lr];

#pragma unroll 2
    for (int k0 = 0; k0 < C_; k0 += 32) {
        bf16x8 fah[4], fal[4], fbh[4], fbl[4];
#pragma unroll
        for (int mf = 0; mf < 4; ++mf) {
            fah[mf] = *(const bf16x8*)&xh[aoff[mf] + k0];
            fal[mf] = *(const bf16x8*)&xl[aoff[mf] + k0];
        }
#pragma unroll
        for (int nf = 0; nf < 4; ++nf) {
            fbh[nf] = *(const bf16x8*)&Wh[boff[nf] + k0];
            fbl[nf] = *(const bf16x8*)&Wl[boff[nf] + k0];
        }
#pragma unroll
        for (int mf = 0; mf < 4; ++mf)
#pragma unroll
            for (int nf = 0; nf < 4; ++nf) {
                acc[mf][nf] = __builtin_amdgcn_mfma_f32_16x16x32_bf16(
                    fah[mf], fbh[nf], acc[mf][nf], 0, 0, 0);
                acc[mf][nf] = __builtin_amdgcn_mfma_f32_16x16x32_bf16(
                    fal[mf], fbh[nf], acc[mf][nf], 0, 0, 0);
                acc[mf][nf] = __builtin_amdgcn_mfma_f32_16x16x32_bf16(
                    fah[mf], fbl[nf], acc[mf][nf], 0, 0, 0);
            }
    }

    // ---- XW tile -> sP[n][m] swizzled bf16-pair (transpose for stage-2 B operand)
#pragma unroll
    for (int mf = 0; mf < 4; ++mf) {
        int gm = wm * 8 + mf * 2 + (lq >> 1);
        int moff = (lq & 1) * 4;
#pragma unroll
        for (int nf = 0; nf < 4; ++nf) {
            int n = wn * 64 + nf * 16 + lr;
            int addr = n * 128 + ((gm ^ (n & 15)) << 3) + moff;
            ushort4 hu, lu;
            float y0 = acc[mf][nf][0], y1 = acc[mf][nf][1];
            float y2 = acc[mf][nf][2], y3 = acc[mf][nf][3];
            hu.x = f2b(y0); lu.x = f2b(y0 - b2f(hu.x));
            hu.y = f2b(y1); lu.y = f2b(y1 - b2f(hu.y));
            hu.z = f2b(y2); lu.z = f2b(y2 - b2f(hu.z));
            hu.w = f2b(y3); lu.w = f2b(y3 - b2f(hu.w));
            *(ushort4*)&sPh[addr] = hu;
            *(ushort4*)&sPl[addr] = lu;
        }
    }
    __syncthreads();

    // ---- stage 2: acc2 = A(128x128) @ XW(tile); A frags direct from L2
    f32x4 acc2[4][4];
#pragma unroll
    for (int i = 0; i < 4; ++i)
#pragma unroll
        for (int j = 0; j < 4; ++j) acc2[i][j] = (f32x4){0.f, 0.f, 0.f, 0.f};

#pragma unroll 2
    for (int kk = 0; kk < 4; ++kk) {
        bf16x8 gah[4], gal[4], gbh[4], gbl[4];
#pragma unroll
        for (int mf = 0; mf < 4; ++mf) {
            int row = wm * 64 + mf * 16 + lr;
            gah[mf] = *(const bf16x8*)&Agh[row * NNODE + kk * 32 + lq * 8];
            gal[mf] = *(const bf16x8*)&Agl[row * NNODE + kk * 32 + lq * 8];
        }
#pragma unroll
        for (int nf = 0; nf < 4; ++nf) {
            int n = wn * 64 + nf * 16 + lr;
            int g = (((kk * 4 + lq) ^ (n & 15)) << 3);
            gbh[nf] = *(const bf16x8*)&sPh[n * 128 + g];
            gbl[nf] = *(const bf16x8*)&sPl[n * 128 + g];
        }
#pragma unroll
        for (int mf = 0; mf < 4; ++mf)
#pragma unroll
            for (int nf = 0; nf < 4; ++nf) {
                acc2[mf][nf] = __builtin_amdgcn_mfma_f32_16x16x32_bf16(
                    gah[mf], gbh[nf], acc2[mf][nf], 0, 0, 0);
                acc2[mf][nf] = __builtin_amdgcn_mfma_f32_16x16x32_bf16(
                    gal[mf], gbh[nf], acc2[mf][nf], 0, 0, 0);
                acc2[mf][nf] = __builtin_amdgcn_mfma_f32_16x16x32_bf16(
                    gah[mf], gbl[nf], acc2[mf][nf], 0, 0, 0);
            }
    }

    // ---- bias + relu + transpose epilogue, two n-halves of 64
    for (int h = 0; h < 2; ++h) {
        __syncthreads();
        if (wn == h) {
#pragma unroll
            for (int mf = 0; mf < 4; ++mf)
#pragma unroll
                for (int nf = 0; nf < 4; ++nf) {
                    int mb = wm * 64 + mf * 16 + lq * 4;
                    int nn = nf * 16 + lr;
#pragma unroll
                    for (int r = 0; r < 4; ++r) {
                        float y = fmaxf(acc2[mf][nf][r] + bv[nf], 0.0f);
                        sT[(mb + r) * 68 + nn] = y;
                    }
                }
        }
        __syncthreads();
        {
            const int m = t >> 1, hw = t & 1;
            const float* rp = &sT[m * 68 + hw * 32];
            ushort hs[32], ls[32];
#pragma unroll
            for (int j = 0; j < 32; ++j) {
                float y = rp[j];
                hs[j] = f2b(y);
                ls[j] = f2b(y - b2f(hs[j]));
            }
            size_t o = ((size_t)(b * NNODE + m)) * C_ + bn + h * 64 + hw * 32;
#pragma unroll
            for (int g = 0; g < 4; ++g) {
                *(int4*)&Yh[o + g * 8] = *(int4*)&hs[g * 8];
                *(int4*)&Yl[o + g * 8] = *(int4*)&ls[g * 8];
            }
        }
    }
}

// ---------------- LayerNorm + transposed write-out ----------------
__global__ __launch_bounds__(256) void ln_out_k(const ushort* __restrict__ xh,
                                                const ushort* __restrict__ xl,
                                                const float* __restrict__ lw,
                                                const float* __restrict__ lb,
                                                float* __restrict__ out) {
    __shared__ float tile[64][68];
    __shared__ float muA[64], invA[64];
    const int t = threadIdx.x, lane = t & 63, wv = t >> 6;
    const int s = blockIdx.x >> 6, b = blockIdx.x & 63;

    for (int i = 0; i < 16; ++i) {
        int p = wv * 16 + i;
        size_t row = ((size_t)(b * NNODE + s * 64 + p)) * C_;
        int c = lane * 8;
        int4 hh = *(const int4*)&xh[row + c];
        int4 llv = *(const int4*)&xl[row + c];
        ushort* hp = (ushort*)&hh;
        ushort* lp = (ushort*)&llv;
        float s1 = 0.f, s2 = 0.f;
#pragma unroll
        for (int j = 0; j < 8; ++j) {
            float v = b2f(hp[j]) + b2f(lp[j]);
            s1 += v;
            s2 += v * v;
        }
#pragma unroll
        for (int off = 32; off; off >>= 1) {
            s1 += __shfl_xor(s1, off);
            s2 += __shfl_xor(s2, off);
        }
        if (lane == 0) {
            float mu = s1 * (1.0f / C_);
            muA[p] = mu;
            invA[p] = rsqrtf(s2 * (1.0f / C_) - mu * mu + EPS_);
        }
    }
    __syncthreads();

    size_t ob = (size_t)s * (B_ * C_ * 64) + (size_t)b * (C_ * 64);
    for (int ct = 0; ct < 8; ++ct) {
        {
            int p = t >> 2, cp = (t & 3) * 16;
            size_t row = ((size_t)(b * NNODE + s * 64 + p)) * C_ + ct * 64 + cp;
            int4 h0 = *(const int4*)&xh[row];
            int4 h1 = *(const int4*)&xh[row + 8];
            int4 l0 = *(const int4*)&xl[row];
            int4 l1 = *(const int4*)&xl[row + 8];
            ushort* hp0 = (ushort*)&h0;
            ushort* hp1 = (ushort*)&h1;
            ushort* lp0 = (ushort*)&l0;
            ushort* lp1 = (ushort*)&l1;
#pragma unroll
            for (int j = 0; j < 8; ++j) tile[p][cp + j] = b2f(hp0[j]) + b2f(lp0[j]);
#pragma unroll
            for (int j = 0; j < 8; ++j) tile[p][cp + 8 + j] = b2f(hp1[j]) + b2f(lp1[j]);
        }
        __syncthreads();
        {
            int p = t & 63, cr = t >> 6;
            float mu = muA[p], inv = invA[p];
#pragma unroll
            for (int k2 = 0; k2 < 16; ++k2) {
                int cl = cr + k2 * 4;
                int c = ct * 64 + cl;
                float v = (tile[p][cl] - mu) * inv * lw[c] + lb[c];
                out[ob + (size_t)c * 64 + p] = v;
            }
        }
        __syncthreads();
    }
}

// ---------------- launch ----------------

extern "C" void kernel_launch(void* const* d_in, const int* in_sizes, int n_in,
                              void* d_out, int out_size, void* d_ws, size_t ws_size,
                              hipStream_t stream) {
    const float* rgb = (const float*)d_in[0];
    const float* ir  = (const float*)d_in[1];
    const int*   ei  = (const int*)d_in[2];
    const float* pos = (const float*)d_in[3];
    const float* Wg  = (const float*)d_in[4];
    const float* bg  = (const float*)d_in[5];
    const float* lw  = (const float*)d_in[6];
    const float* lb  = (const float*)d_in[7];
    float* out = (float*)d_out;

    char* ws = (char*)d_ws;
    ushort* x0h  = (ushort*)(ws);
    ushort* x0l  = (ushort*)(ws + 8388608);
    ushort* x1h  = (ushort*)(ws + 16777216);
    ushort* x1l  = (ushort*)(ws + 25165824);
    ushort* WTh  = (ushort*)(ws + 33554432);
    ushort* WTl  = (ushort*)(ws + 37748736);
    float*  Afp  = (float*)(ws + 41943040);
    float*  deg  = Afp + NNODE * NNODE;
    ushort* Ahn  = (ushort*)(ws + 42009088);
    ushort* Aln  = (ushort*)(ws + 42041856);

    zero_k<<<(NNODE * NNODE + NNODE + 255) / 256, 256, 0, stream>>>(Afp, NNODE * NNODE + NNODE);
    count_deg_k<<<(NEDGE + 255) / 256, 256, 0, stream>>>(ei, deg);
    dinv_k<<<1, NNODE, 0, stream>>>(deg);
    build_A_k<<<(NEDGE + NNODE + 255) / 256, 256, 0, stream>>>(ei, deg, Afp);
    splitA_k<<<(NNODE * NNODE + 255) / 256, 256, 0, stream>>>(Afp, Ahn, Aln);

    wprep_k<<<dim3(8, 8, NLAYERS), 256, 0, stream>>>(Wg, WTh, WTl);
    pool_x_k<<<dim3(16, B_), 256, 0, stream>>>(rgb, ir, pos, x0h, x0l);

    for (int l = 0; l < NLAYERS; ++l) {
        const ushort* inh = (l & 1) ? x1h : x0h;
        const ushort* inl = (l & 1) ? x1l : x0l;
        ushort* outh = (l & 1) ? x0h : x1h;
        ushort* outl = (l & 1) ? x0l : x1l;
        gemm_fused_k<<<dim3(4, B_), 256, 0, stream>>>(
            inh, inl, WTh + (size_t)l * C_ * C_, WTl + (size_t)l * C_ * C_,
            Ahn, Aln, bg + (size_t)l * C_, outh, outl);
    }

    ln_out_k<<<2 * B_, 256, 0, stream>>>(x0h, x0l, lw, lb, out);
}

// Round 5
// 332.186 us; speedup vs baseline: 1.4010x; 1.4010x over previous
//
#include <hip/hip_runtime.h>

#define B_      64
#define C_      512
#define NNODE   128
#define NEDGE   1024
#define NLAYERS 8
#define EPS_    1e-5f

typedef __attribute__((ext_vector_type(8))) short bf16x8;
typedef __attribute__((ext_vector_type(4))) float f32x4;

__device__ __forceinline__ ushort f2b(float x) {
    unsigned u = __builtin_bit_cast(unsigned, x);
    unsigned r = (u + 0x7fffu + ((u >> 16) & 1u)) >> 16;
    return (ushort)r;
}
__device__ __forceinline__ float b2f(ushort h) {
    unsigned u = ((unsigned)h) << 16;
    return __builtin_bit_cast(float, u);
}

// ---------------- graph prep ----------------

__global__ void zero_k(float* __restrict__ p, int n) {
    int i = blockIdx.x * 256 + threadIdx.x;
    if (i < n) p[i] = 0.0f;
}

__global__ void count_deg_k(const int* __restrict__ ei, float* __restrict__ deg) {
    int e = blockIdx.x * 256 + threadIdx.x;
    if (e < NEDGE) atomicAdd(&deg[ei[NEDGE + e]], 1.0f);
}

__global__ void dinv_k(float* __restrict__ deg) {
    int n = threadIdx.x;
    deg[n] = 1.0f / sqrtf(deg[n] + 1.0f);
}

__global__ void build_A_k(const int* __restrict__ ei, const float* __restrict__ dinv,
                          float* __restrict__ A) {
    int e = blockIdx.x * 256 + threadIdx.x;
    if (e < NEDGE) {
        int s = ei[e];
        int d = ei[NEDGE + e];
        atomicAdd(&A[d * NNODE + s], dinv[s] * dinv[d]);
    } else if (e < NEDGE + NNODE) {
        int n = e - NEDGE;
        atomicAdd(&A[n * NNODE + n], dinv[n] * dinv[n]);
    }
}

__global__ void splitA_k(const float* __restrict__ A, ushort* __restrict__ Ah,
                         ushort* __restrict__ Al) {
    int i = blockIdx.x * 256 + threadIdx.x;
    if (i < NNODE * NNODE) {
        float v = A[i];
        ushort h = f2b(v);
        Ah[i] = h;
        Al[i] = f2b(v - b2f(h));
    }
}

// ---------------- W transpose + split: WT[l][n][k] = W[l][k][n] ----------------
__global__ __launch_bounds__(256) void wprep_k(const float* __restrict__ W,
                                               ushort* __restrict__ WTh,
                                               ushort* __restrict__ WTl) {
    __shared__ float tl[64][68];
    const int t = threadIdx.x;
    const int n0 = blockIdx.x * 64, k0 = blockIdx.y * 64, l = blockIdx.z;
    const float* Wl = W + (size_t)l * C_ * C_;
    {
        int kk = t >> 2, nc = (t & 3) * 16;
        const float* src = Wl + (size_t)(k0 + kk) * C_ + n0 + nc;
#pragma unroll
        for (int g = 0; g < 4; ++g)
            *(float4*)&tl[kk][nc + g * 4] = *(const float4*)(src + g * 4);
    }
    __syncthreads();
    {
        int nn = t >> 2, kc = (t & 3) * 16;
        ushort h[16], lo[16];
#pragma unroll
        for (int j = 0; j < 16; ++j) {
            float v = tl[kc + j][nn];
            h[j] = f2b(v);
            lo[j] = f2b(v - b2f(h[j]));
        }
        size_t o = ((size_t)l * C_ + n0 + nn) * C_ + k0 + kc;
        *(int4*)&WTh[o] = *(int4*)&h[0];
        *(int4*)&WTh[o + 8] = *(int4*)&h[8];
        *(int4*)&WTl[o] = *(int4*)&lo[0];
        *(int4*)&WTl[o + 8] = *(int4*)&lo[8];
    }
}

// ---------------- fused pool + pos + split -> x0 ----------------
// 16 channels (32 planes) per block, grid (32, 64) = 2048 blocks, 8/CU.
// Deep-MLP: 16 loads (4 planes) in flight before any reduction.
__global__ __launch_bounds__(256) void pool_x_k(const float* __restrict__ rgb,
                                                const float* __restrict__ ir,
                                                const float* __restrict__ pos,
                                                ushort* __restrict__ xh,
                                                ushort* __restrict__ xl) {
    __shared__ float lds[16][132];
    const int t = threadIdx.x, l = t & 63, wv = t >> 6;
    const int c0 = blockIdx.x * 16, b = blockIdx.y;

#pragma unroll
    for (int grp = 0; grp < 2; ++grp) {
        float4 v[4][4];
#pragma unroll
        for (int j = 0; j < 4; ++j) {
            int p = wv * 8 + grp * 4 + j;
            int src = p >> 4, cc = p & 15;
            const float* base = (src ? ir : rgb)
                + ((size_t)(b * C_ + c0 + cc)) * 1024 + l * 4;
#pragma unroll
            for (int g = 0; g < 4; ++g)
                v[j][g] = *(const float4*)(base + g * 256);
        }
#pragma unroll
        for (int j = 0; j < 4; ++j) {
            int p = wv * 8 + grp * 4 + j;
            int src = p >> 4, cc = p & 15;
            float s[4];
#pragma unroll
            for (int g = 0; g < 4; ++g) {
                s[g] = v[j][g].x + v[j][g].y + v[j][g].z + v[j][g].w;
                s[g] += __shfl_xor(s[g], 8);
                s[g] += __shfl_xor(s[g], 16);
            }
            if (((l >> 3) & 3) == 0) {
                int ha = l & 7, hi = l >> 5;
#pragma unroll
                for (int g = 0; g < 4; ++g)
                    lds[cc][src * 64 + (2 * g + hi) * 8 + ha] = s[g] * 0.0625f;
            }
        }
    }
    __syncthreads();

    const int n = t >> 1, cb = (t & 1) * 8;
    float4 p0 = *(const float4*)&pos[(size_t)n * C_ + c0 + cb];
    float4 p1 = *(const float4*)&pos[(size_t)n * C_ + c0 + cb + 4];
    float v2[8];
    v2[0] = lds[cb + 0][n] + p0.x; v2[1] = lds[cb + 1][n] + p0.y;
    v2[2] = lds[cb + 2][n] + p0.z; v2[3] = lds[cb + 3][n] + p0.w;
    v2[4] = lds[cb + 4][n] + p1.x; v2[5] = lds[cb + 5][n] + p1.y;
    v2[6] = lds[cb + 6][n] + p1.z; v2[7] = lds[cb + 7][n] + p1.w;
    ushort hs[8], ls[8];
#pragma unroll
    for (int j = 0; j < 8; ++j) {
        hs[j] = f2b(v2[j]);
        ls[j] = f2b(v2[j] - b2f(hs[j]));
    }
    size_t o = ((size_t)(b * NNODE + n)) * C_ + c0 + cb;
    *(int4*)&xh[o] = *(int4*)&hs[0];
    *(int4*)&xl[o] = *(int4*)&ls[0];
}

// ---------------- fused layer: x' = relu(A @ (x @ W) + bias) ----------------
// grid (4 n-tiles of 128, 64 b), 512 thr = 8 waves (2m x 4n), wave tile 64x32.
__global__ __launch_bounds__(512, 2) void gemm_fused_k(
    const ushort* __restrict__ Xh, const ushort* __restrict__ Xl,
    const ushort* __restrict__ Wh, const ushort* __restrict__ Wl,
    const ushort* __restrict__ Agh, const ushort* __restrict__ Agl,
    const float* __restrict__ bias,
    ushort* __restrict__ Yh, ushort* __restrict__ Yl) {
    __shared__ __align__(16) char smem[65536];
    ushort* sXh = (ushort*)smem;                 // [128][40]
    ushort* sXl = (ushort*)(smem + 10240);
    ushort* sWh = (ushort*)(smem + 20480);
    ushort* sWl = (ushort*)(smem + 30720);
    ushort* sPh = (ushort*)smem;                 // [128 n][128 m] granule-swizzled
    ushort* sPl = (ushort*)(smem + 32768);
    float*  sT  = (float*)smem;                  // [128][68] half-tile

    const int t = threadIdx.x, lane = t & 63;
    const int wv = t >> 6, wm = wv >> 2, wn = wv & 3;
    const int lr = lane & 15, lq = lane >> 4;
    const int bn = blockIdx.x * 128, b = blockIdx.y;

    const ushort* xh = Xh + (size_t)b * NNODE * C_;
    const ushort* xl = Xl + (size_t)b * NNODE * C_;

    const int sr = t >> 2;            // staging row 0..127
    const int sk = (t & 3) * 8;       // k-offset (ushorts)

    f32x4 acc[4][2];
#pragma unroll
    for (int i = 0; i < 4; ++i)
#pragma unroll
        for (int j = 0; j < 2; ++j) acc[i][j] = (f32x4){0.f, 0.f, 0.f, 0.f};

    float bv[2];
#pragma unroll
    for (int nf = 0; nf < 2; ++nf) bv[nf] = bias[bn + wn * 32 + nf * 16 + lr];

    int4 rXh, rXl, rWh, rWl;
#define GLOAD(K0)                                                       \
    {                                                                   \
        rXh = *(const int4*)&xh[(size_t)sr * C_ + (K0) + sk];           \
        rXl = *(const int4*)&xl[(size_t)sr * C_ + (K0) + sk];           \
        rWh = *(const int4*)&Wh[(size_t)(bn + sr) * C_ + (K0) + sk];    \
        rWl = *(const int4*)&Wl[(size_t)(bn + sr) * C_ + (K0) + sk];    \
    }

    GLOAD(0)
    for (int k0 = 0; k0 < C_; k0 += 32) {
        __syncthreads();
        *(int4*)&sXh[sr * 40 + sk] = rXh;
        *(int4*)&sXl[sr * 40 + sk] = rXl;
        *(int4*)&sWh[sr * 40 + sk] = rWh;
        *(int4*)&sWl[sr * 40 + sk] = rWl;
        __syncthreads();
        if (k0 + 32 < C_) GLOAD(k0 + 32)

        bf16x8 fah[4], fal[4], fbh[2], fbl[2];
#pragma unroll
        for (int mf = 0; mf < 4; ++mf) {
            int ro = (wm * 64 + mf * 16 + lr) * 40 + lq * 8;
            fah[mf] = *(const bf16x8*)&sXh[ro];
            fal[mf] = *(const bf16x8*)&sXl[ro];
        }
#pragma unroll
        for (int nf = 0; nf < 2; ++nf) {
            int ro = (wn * 32 + nf * 16 + lr) * 40 + lq * 8;
            fbh[nf] = *(const bf16x8*)&sWh[ro];
            fbl[nf] = *(const bf16x8*)&sWl[ro];
        }
#pragma unroll
        for (int mf = 0; mf < 4; ++mf)
#pragma unroll
            for (int nf = 0; nf < 2; ++nf) {
                acc[mf][nf] = __builtin_amdgcn_mfma_f32_16x16x32_bf16(
                    fah[mf], fbh[nf], acc[mf][nf], 0, 0, 0);
                acc[mf][nf] = __builtin_amdgcn_mfma_f32_16x16x32_bf16(
                    fal[mf], fbh[nf], acc[mf][nf], 0, 0, 0);
                acc[mf][nf] = __builtin_amdgcn_mfma_f32_16x16x32_bf16(
                    fah[mf], fbl[nf], acc[mf][nf], 0, 0, 0);
            }
    }
#undef GLOAD

    // ---- XW tile -> sP[n][m] swizzled bf16-pair
    __syncthreads();
#pragma unroll
    for (int mf = 0; mf < 4; ++mf) {
        int gm = wm * 8 + mf * 2 + (lq >> 1);
        int moff = (lq & 1) * 4;
#pragma unroll
        for (int nf = 0; nf < 2; ++nf) {
            int n = wn * 32 + nf * 16 + lr;
            int addr = n * 128 + ((gm ^ (n & 15)) << 3) + moff;
            ushort4 hu, lu;
            float y0 = acc[mf][nf][0], y1 = acc[mf][nf][1];
            float y2 = acc[mf][nf][2], y3 = acc[mf][nf][3];
            hu.x = f2b(y0); lu.x = f2b(y0 - b2f(hu.x));
            hu.y = f2b(y1); lu.y = f2b(y1 - b2f(hu.y));
            hu.z = f2b(y2); lu.z = f2b(y2 - b2f(hu.z));
            hu.w = f2b(y3); lu.w = f2b(y3 - b2f(hu.w));
            *(ushort4*)&sPh[addr] = hu;
            *(ushort4*)&sPl[addr] = lu;
        }
    }
    __syncthreads();

    // ---- stage 2: acc2 = A(128x128) @ XW(tile); A frags from L2
    f32x4 acc2[4][2];
#pragma unroll
    for (int i = 0; i < 4; ++i)
#pragma unroll
        for (int j = 0; j < 2; ++j) acc2[i][j] = (f32x4){0.f, 0.f, 0.f, 0.f};

#pragma unroll
    for (int kk = 0; kk < 4; ++kk) {
        bf16x8 gah[4], gal[4], gbh[2], gbl[2];
#pragma unroll
        for (int mf = 0; mf < 4; ++mf) {
            int row = wm * 64 + mf * 16 + lr;
            gah[mf] = *(const bf16x8*)&Agh[row * NNODE + kk * 32 + lq * 8];
            gal[mf] = *(const bf16x8*)&Agl[row * NNODE + kk * 32 + lq * 8];
        }
#pragma unroll
        for (int nf = 0; nf < 2; ++nf) {
            int n = wn * 32 + nf * 16 + lr;
            int g = (((kk * 4 + lq) ^ (n & 15)) << 3);
            gbh[nf] = *(const bf16x8*)&sPh[n * 128 + g];
            gbl[nf] = *(const bf16x8*)&sPl[n * 128 + g];
        }
#pragma unroll
        for (int mf = 0; mf < 4; ++mf)
#pragma unroll
            for (int nf = 0; nf < 2; ++nf) {
                acc2[mf][nf] = __builtin_amdgcn_mfma_f32_16x16x32_bf16(
                    gah[mf], gbh[nf], acc2[mf][nf], 0, 0, 0);
                acc2[mf][nf] = __builtin_amdgcn_mfma_f32_16x16x32_bf16(
                    gal[mf], gbh[nf], acc2[mf][nf], 0, 0, 0);
                acc2[mf][nf] = __builtin_amdgcn_mfma_f32_16x16x32_bf16(
                    gah[mf], gbl[nf], acc2[mf][nf], 0, 0, 0);
            }
    }

    // ---- bias + relu + transpose epilogue, two n-halves of 64
#pragma unroll
    for (int h = 0; h < 2; ++h) {
        __syncthreads();
        if ((wn >> 1) == h) {
#pragma unroll
            for (int mf = 0; mf < 4; ++mf)
#pragma unroll
                for (int nf = 0; nf < 2; ++nf) {
                    int mb = wm * 64 + mf * 16 + lq * 4;
                    int nl = (wn & 1) * 32 + nf * 16 + lr;
#pragma unroll
                    for (int r = 0; r < 4; ++r) {
                        float y = fmaxf(acc2[mf][nf][r] + bv[nf], 0.0f);
                        sT[(mb + r) * 68 + nl] = y;
                    }
                }
        }
        __syncthreads();
        {
            const int m = t >> 2, seg = t & 3;
            const float* rp = &sT[m * 68 + seg * 16];
            ushort hs[16], ls[16];
#pragma unroll
            for (int j = 0; j < 16; ++j) {
                float y = rp[j];
                hs[j] = f2b(y);
                ls[j] = f2b(y - b2f(hs[j]));
            }
            size_t o = ((size_t)(b * NNODE + m)) * C_ + bn + h * 64 + seg * 16;
            *(int4*)&Yh[o] = *(int4*)&hs[0];
            *(int4*)&Yh[o + 8] = *(int4*)&hs[8];
            *(int4*)&Yl[o] = *(int4*)&ls[0];
            *(int4*)&Yl[o + 8] = *(int4*)&ls[8];
        }
    }
}

// ---------------- LayerNorm + transposed write-out ----------------
__global__ __launch_bounds__(256) void ln_out_k(const ushort* __restrict__ xh,
                                                const ushort* __restrict__ xl,
                                                const float* __restrict__ lw,
                                                const float* __restrict__ lb,
                                                float* __restrict__ out) {
    __shared__ float tile[64][68];
    __shared__ float muA[64], invA[64];
    const int t = threadIdx.x, lane = t & 63, wv = t >> 6;
    const int s = blockIdx.x >> 6, b = blockIdx.x & 63;

    for (int i = 0; i < 16; ++i) {
        int p = wv * 16 + i;
        size_t row = ((size_t)(b * NNODE + s * 64 + p)) * C_;
        int c = lane * 8;
        int4 hh = *(const int4*)&xh[row + c];
        int4 llv = *(const int4*)&xl[row + c];
        ushort* hp = (ushort*)&hh;
        ushort* lp = (ushort*)&llv;
        float s1 = 0.f, s2 = 0.f;
#pragma unroll
        for (int j = 0; j < 8; ++j) {
            float v = b2f(hp[j]) + b2f(lp[j]);
            s1 += v;
            s2 += v * v;
        }
#pragma unroll
        for (int off = 32; off; off >>= 1) {
            s1 += __shfl_xor(s1, off);
            s2 += __shfl_xor(s2, off);
        }
        if (lane == 0) {
            float mu = s1 * (1.0f / C_);
            muA[p] = mu;
            invA[p] = rsqrtf(s2 * (1.0f / C_) - mu * mu + EPS_);
        }
    }
    __syncthreads();

    size_t ob = (size_t)s * (B_ * C_ * 64) + (size_t)b * (C_ * 64);
    for (int ct = 0; ct < 8; ++ct) {
        {
            int p = t >> 2, cp = (t & 3) * 16;
            size_t row = ((size_t)(b * NNODE + s * 64 + p)) * C_ + ct * 64 + cp;
            int4 h0 = *(const int4*)&xh[row];
            int4 h1 = *(const int4*)&xh[row + 8];
            int4 l0 = *(const int4*)&xl[row];
            int4 l1 = *(const int4*)&xl[row + 8];
            ushort* hp0 = (ushort*)&h0;
            ushort* hp1 = (ushort*)&h1;
            ushort* lp0 = (ushort*)&l0;
            ushort* lp1 = (ushort*)&l1;
#pragma unroll
            for (int j = 0; j < 8; ++j) tile[p][cp + j] = b2f(hp0[j]) + b2f(lp0[j]);
#pragma unroll
            for (int j = 0; j < 8; ++j) tile[p][cp + 8 + j] = b2f(hp1[j]) + b2f(lp1[j]);
        }
        __syncthreads();
        {
            int p = t & 63, cr = t >> 6;
            float mu = muA[p], inv = invA[p];
#pragma unroll
            for (int k2 = 0; k2 < 16; ++k2) {
                int cl = cr + k2 * 4;
                int c = ct * 64 + cl;
                float v = (tile[p][cl] - mu) * inv * lw[c] + lb[c];
                out[ob + (size_t)c * 64 + p] = v;
            }
        }
        __syncthreads();
    }
}

// ---------------- launch ----------------

extern "C" void kernel_launch(void* const* d_in, const int* in_sizes, int n_in,
                              void* d_out, int out_size, void* d_ws, size_t ws_size,
                              hipStream_t stream) {
    const float* rgb = (const float*)d_in[0];
    const float* ir  = (const float*)d_in[1];
    const int*   ei  = (const int*)d_in[2];
    const float* pos = (const float*)d_in[3];
    const float* Wg  = (const float*)d_in[4];
    const float* bg  = (const float*)d_in[5];
    const float* lw  = (const float*)d_in[6];
    const float* lb  = (const float*)d_in[7];
    float* out = (float*)d_out;

    char* ws = (char*)d_ws;
    ushort* x0h  = (ushort*)(ws);
    ushort* x0l  = (ushort*)(ws + 8388608);
    ushort* x1h  = (ushort*)(ws + 16777216);
    ushort* x1l  = (ushort*)(ws + 25165824);
    ushort* WTh  = (ushort*)(ws + 33554432);
    ushort* WTl  = (ushort*)(ws + 37748736);
    float*  Afp  = (float*)(ws + 41943040);
    float*  deg  = Afp + NNODE * NNODE;
    ushort* Ahn  = (ushort*)(ws + 42009088);
    ushort* Aln  = (ushort*)(ws + 42041856);

    zero_k<<<(NNODE * NNODE + NNODE + 255) / 256, 256, 0, stream>>>(Afp, NNODE * NNODE + NNODE);
    count_deg_k<<<(NEDGE + 255) / 256, 256, 0, stream>>>(ei, deg);
    dinv_k<<<1, NNODE, 0, stream>>>(deg);
    build_A_k<<<(NEDGE + NNODE + 255) / 256, 256, 0, stream>>>(ei, deg, Afp);
    splitA_k<<<(NNODE * NNODE + 255) / 256, 256, 0, stream>>>(Afp, Ahn, Aln);

    wprep_k<<<dim3(8, 8, NLAYERS), 256, 0, stream>>>(Wg, WTh, WTl);
    pool_x_k<<<dim3(32, B_), 256, 0, stream>>>(rgb, ir, pos, x0h, x0l);

    for (int l = 0; l < NLAYERS; ++l) {
        const ushort* inh = (l & 1) ? x1h : x0h;
        const ushort* inl = (l & 1) ? x1l : x0l;
        ushort* outh = (l & 1) ? x0h : x1h;
        ushort* outl = (l & 1) ? x0l : x1l;
        gemm_fused_k<<<dim3(4, B_), 512, 0, stream>>>(
            inh, inl, WTh + (size_t)l * C_ * C_, WTl + (size_t)l * C_ * C_,
            Ahn, Aln, bg + (size_t)l * C_, outh, outl);
    }

    ln_out_k<<<2 * B_, 256, 0, stream>>>(x0h, x0l, lw, lb, out);
}

// Round 7
// 301.336 us; speedup vs baseline: 1.5444x; 1.1024x over previous
//
#include <hip/hip_runtime.h>

#define B_      64
#define C_      512
#define NNODE   128
#define NEDGE   1024
#define NLAYERS 8
#define EPS_    1e-5f

typedef __attribute__((ext_vector_type(8))) short bf16x8;
typedef __attribute__((ext_vector_type(4))) float f32x4;

__device__ __forceinline__ ushort f2b(float x) {
    unsigned u = __builtin_bit_cast(unsigned, x);
    unsigned r = (u + 0x7fffu + ((u >> 16) & 1u)) >> 16;
    return (ushort)r;
}
__device__ __forceinline__ float b2f(ushort h) {
    unsigned u = ((unsigned)h) << 16;
    return __builtin_bit_cast(float, u);
}

// Fragment layout for a [rows][512] bf16 matrix consumed as MFMA A/B operand:
//   frag[rowblk][mf][ks][lane][8]   lane=(lq<<4)|lr
//   element (row = base + mf*16 + lr, k = ks*32 + lq*8 + j)
// Every wave fragment load = base + lane*16B -> one coalesced 1KB transaction.

// ---------------- graph prep ----------------

__global__ void zero_k(float* __restrict__ p, int n) {
    int i = blockIdx.x * 256 + threadIdx.x;
    if (i < n) p[i] = 0.0f;
}

__global__ void count_deg_k(const int* __restrict__ ei, float* __restrict__ deg) {
    int e = blockIdx.x * 256 + threadIdx.x;
    if (e < NEDGE) atomicAdd(&deg[ei[NEDGE + e]], 1.0f);
}

__global__ void dinv_k(float* __restrict__ deg) {
    int n = threadIdx.x;
    deg[n] = 1.0f / sqrtf(deg[n] + 1.0f);
}

__global__ void build_A_k(const int* __restrict__ ei, const float* __restrict__ dinv,
                          float* __restrict__ A) {
    int e = blockIdx.x * 256 + threadIdx.x;
    if (e < NEDGE) {
        int s = ei[e];
        int d = ei[NEDGE + e];
        atomicAdd(&A[d * NNODE + s], dinv[s] * dinv[d]);
    } else if (e < NEDGE + NNODE) {
        int n = e - NEDGE;
        atomicAdd(&A[n * NNODE + n], dinv[n] * dinv[n]);
    }
}

// A(128x128 fp32) -> frag layout [wm2][mf4][kk4][lane64][8], split h/l
__global__ void splitAfrag_k(const float* __restrict__ A, ushort* __restrict__ Ah,
                             ushort* __restrict__ Al) {
    int gid = blockIdx.x * 256 + threadIdx.x;   // 0..2047
    if (gid >= 2048) return;
    int lane = gid & 63, lr = lane & 15, lq = lane >> 4;
    int kk = (gid >> 6) & 3, mf = (gid >> 8) & 3, wm = (gid >> 10) & 1;
    int row = wm * 64 + mf * 16 + lr;
    int k = kk * 32 + lq * 8;
    ushort hh[8], ll[8];
#pragma unroll
    for (int j = 0; j < 8; ++j) {
        float v = A[row * NNODE + k + j];
        hh[j] = f2b(v);
        ll[j] = f2b(v - b2f(hh[j]));
    }
    *(int4*)&Ah[(size_t)gid * 8] = *(int4*)hh;
    *(int4*)&Al[(size_t)gid * 8] = *(int4*)ll;
}

// ---------------- W -> frag layout + split ----------------
// Wf[l][ntile4][wn4][nf2][ks16][lane64][8], element (n,k)=W[k][n]
__global__ __launch_bounds__(256) void wprep_k(const float* __restrict__ W,
                                               ushort* __restrict__ Wfh,
                                               ushort* __restrict__ Wfl) {
    __shared__ float tl[64][68];
    const int t = threadIdx.x;
    const int n0 = blockIdx.x * 64, k0 = blockIdx.y * 64, l = blockIdx.z;
    const float* Wl = W + (size_t)l * C_ * C_;
    {
        int kk = t >> 2, nc = (t & 3) * 16;
        const float* src = Wl + (size_t)(k0 + kk) * C_ + n0 + nc;
#pragma unroll
        for (int g = 0; g < 4; ++g)
            *(float4*)&tl[kk][nc + g * 4] = *(const float4*)(src + g * 4);
    }
    __syncthreads();
    {
        int nn = t >> 2, kc = (t & 3) * 16;
        int n = n0 + nn;
        int ntile = n >> 7, wn = (n >> 5) & 3, nf = (n >> 4) & 1, lr = n & 15;
        ushort h[16], lo[16];
#pragma unroll
        for (int j = 0; j < 16; ++j) {
            float v = tl[kc + j][nn];
            h[j] = f2b(v);
            lo[j] = f2b(v - b2f(h[j]));
        }
#pragma unroll
        for (int g = 0; g < 2; ++g) {
            int kb = k0 + kc + g * 8;
            int ks = kb >> 5, lq = (kb >> 3) & 3;
            size_t o = (((((size_t)l * 4 + ntile) * 4 + wn) * 2 + nf) * 16 + ks) * 512
                     + (lq * 16 + lr) * 8;
            *(int4*)&Wfh[o] = *(int4*)&h[g * 8];
            *(int4*)&Wfl[o] = *(int4*)&lo[g * 8];
        }
    }
}

// ---------------- fused pool + pos + split -> x0 (frag layout) ----------------
// 32 channels/block, grid (16, 64). nontemporal streaming loads.
__global__ __launch_bounds__(256) void pool_x_k(const float* __restrict__ rgb,
                                                const float* __restrict__ ir,
                                                const float* __restrict__ pos,
                                                ushort* __restrict__ xh,
                                                ushort* __restrict__ xl) {
    __shared__ float lds[32][130];
    const int t = threadIdx.x, l = t & 63, wv = t >> 6;
    const int c0 = blockIdx.x * 32, b = blockIdx.y;

    for (int i = 0; i < 16; ++i) {
        int p = wv * 16 + i;
        int src = p >> 5, cc = p & 31;
        const float* base = (src ? ir : rgb) + ((size_t)(b * C_ + c0 + cc)) * 1024 + l * 4;
        float s[4];
#pragma unroll
        for (int g = 0; g < 4; ++g) {
            f32x4 v = __builtin_nontemporal_load((const f32x4*)(base + g * 256));
            s[g] = v.x + v.y + v.z + v.w;
        }
#pragma unroll
        for (int g = 0; g < 4; ++g) {
            s[g] += __shfl_xor(s[g], 8);
            s[g] += __shfl_xor(s[g], 16);
        }
        if (((l >> 3) & 3) == 0) {
            int ha = l & 7, hi = l >> 5;
#pragma unroll
            for (int g = 0; g < 4; ++g)
                lds[cc][src * 64 + (2 * g + hi) * 8 + ha] = s[g] * 0.0625f;
        }
    }
    __syncthreads();

    const int n = t >> 1, cb = (t & 1) * 16;
    float v[16];
#pragma unroll
    for (int j = 0; j < 16; j += 4) {
        float4 pv = *(const float4*)&pos[(size_t)n * C_ + c0 + cb + j];
        v[j + 0] = lds[cb + j + 0][n] + pv.x;
        v[j + 1] = lds[cb + j + 1][n] + pv.y;
        v[j + 2] = lds[cb + j + 2][n] + pv.z;
        v[j + 3] = lds[cb + j + 3][n] + pv.w;
    }
    ushort hs[16], ls[16];
#pragma unroll
    for (int j = 0; j < 16; ++j) {
        hs[j] = f2b(v[j]);
        ls[j] = f2b(v[j] - b2f(hs[j]));
    }
    // frag-layout stores: granule = 8 channels
    const int wm = n >> 6, mf = (n >> 4) & 3, lr = n & 15;
    const int ks = blockIdx.x;   // c0 = 32*bx -> ks = bx
#pragma unroll
    for (int g = 0; g < 2; ++g) {
        int lq = ((cb + g * 8) >> 3) & 3;
        size_t o = (((size_t)(b * 2 + wm) * 4 + mf) * 16 + ks) * 512 + (lq * 16 + lr) * 8;
        *(int4*)&xh[o] = *(int4*)&hs[g * 8];
        *(int4*)&xl[o] = *(int4*)&ls[g * 8];
    }
}

// ---------------- fused layer: x' = relu(A @ (x @ W) + bias) ----------------
// grid (4 ntile, 64 b), 512 thr = 8 waves (2m x 4n), wave tile 64x32.
// Stage-1 operands fragment-direct from global (pre-swizzled) - no LDS, no barriers.
__global__ __launch_bounds__(512, 2) void gemm_fused_k(
    const ushort* __restrict__ Xfh, const ushort* __restrict__ Xfl,
    const ushort* __restrict__ Wfh, const ushort* __restrict__ Wfl,
    const ushort* __restrict__ Afh, const ushort* __restrict__ Afl,
    const float* __restrict__ bias,
    ushort* __restrict__ Yfh, ushort* __restrict__ Yfl) {
    __shared__ __align__(16) char smem[65536];
    ushort* sPh = (ushort*)smem;                 // [128 n][128 m] granule-swizzled
    ushort* sPl = (ushort*)(smem + 32768);
    float*  sT  = (float*)smem;                  // [128][68] half-tile

    const int t = threadIdx.x, lane = t & 63;
    const int wv = t >> 6, wm = wv >> 2, wn = wv & 3;
    const int lr = lane & 15, lq = lane >> 4;
    const int ntile = blockIdx.x, bn = ntile * 128, b = blockIdx.y;

    // stage-1 fragment bases (ushort indices); ks stride 512, mf/nf stride 8192
    const size_t xb = ((size_t)(b * 2 + wm) * 4) * 8192 + lane * 8;
    const size_t wb = ((size_t)(ntile * 4 + wn) * 2) * 8192 + lane * 8;

    f32x4 acc[4][2];
#pragma unroll
    for (int i = 0; i < 4; ++i)
#pragma unroll
        for (int j = 0; j < 2; ++j) acc[i][j] = (f32x4){0.f, 0.f, 0.f, 0.f};

    float bv[2];
#pragma unroll
    for (int nf = 0; nf < 2; ++nf) bv[nf] = bias[bn + wn * 32 + nf * 16 + lr];

#pragma unroll 2
    for (int ks = 0; ks < 16; ++ks) {
        bf16x8 fah[4], fal[4], fbh[2], fbl[2];
#pragma unroll
        for (int mf = 0; mf < 4; ++mf) {
            fah[mf] = *(const bf16x8*)&Xfh[xb + mf * 8192 + ks * 512];
            fal[mf] = *(const bf16x8*)&Xfl[xb + mf * 8192 + ks * 512];
        }
#pragma unroll
        for (int nf = 0; nf < 2; ++nf) {
            fbh[nf] = *(const bf16x8*)&Wfh[wb + nf * 8192 + ks * 512];
            fbl[nf] = *(const bf16x8*)&Wfl[wb + nf * 8192 + ks * 512];
        }
#pragma unroll
        for (int mf = 0; mf < 4; ++mf)
#pragma unroll
            for (int nf = 0; nf < 2; ++nf) {
                acc[mf][nf] = __builtin_amdgcn_mfma_f32_16x16x32_bf16(
                    fah[mf], fbh[nf], acc[mf][nf], 0, 0, 0);
                acc[mf][nf] = __builtin_amdgcn_mfma_f32_16x16x32_bf16(
                    fal[mf], fbh[nf], acc[mf][nf], 0, 0, 0);
                acc[mf][nf] = __builtin_amdgcn_mfma_f32_16x16x32_bf16(
                    fah[mf], fbl[nf], acc[mf][nf], 0, 0, 0);
            }
    }

    // ---- XW tile -> sP[n][m] swizzled bf16-pair (transpose for stage-2 B operand)
#pragma unroll
    for (int mf = 0; mf < 4; ++mf) {
        int gm = wm * 8 + mf * 2 + (lq >> 1);
        int moff = (lq & 1) * 4;
#pragma unroll
        for (int nf = 0; nf < 2; ++nf) {
            int n = wn * 32 + nf * 16 + lr;
            int addr = n * 128 + ((gm ^ (n & 15)) << 3) + moff;
            ushort4 hu, lu;
            float y0 = acc[mf][nf][0], y1 = acc[mf][nf][1];
            float y2 = acc[mf][nf][2], y3 = acc[mf][nf][3];
            hu.x = f2b(y0); lu.x = f2b(y0 - b2f(hu.x));
            hu.y = f2b(y1); lu.y = f2b(y1 - b2f(hu.y));
            hu.z = f2b(y2); lu.z = f2b(y2 - b2f(hu.z));
            hu.w = f2b(y3); lu.w = f2b(y3 - b2f(hu.w));
            *(ushort4*)&sPh[addr] = hu;
            *(ushort4*)&sPl[addr] = lu;
        }
    }
    __syncthreads();

    // ---- stage 2: acc2 = A(128x128) @ XW(tile); A frags coalesced from L2
    f32x4 acc2[4][2];
#pragma unroll
    for (int i = 0; i < 4; ++i)
#pragma unroll
        for (int j = 0; j < 2; ++j) acc2[i][j] = (f32x4){0.f, 0.f, 0.f, 0.f};

#pragma unroll
    for (int kk = 0; kk < 4; ++kk) {
        bf16x8 gah[4], gal[4], gbh[2], gbl[2];
#pragma unroll
        for (int mf = 0; mf < 4; ++mf) {
            size_t o = (size_t)((wm * 4 + mf) * 4 + kk) * 512 + lane * 8;
            gah[mf] = *(const bf16x8*)&Afh[o];
            gal[mf] = *(const bf16x8*)&Afl[o];
        }
#pragma unroll
        for (int nf = 0; nf < 2; ++nf) {
            int n = wn * 32 + nf * 16 + lr;
            int g = (((kk * 4 + lq) ^ (n & 15)) << 3);
            gbh[nf] = *(const bf16x8*)&sPh[n * 128 + g];
            gbl[nf] = *(const bf16x8*)&sPl[n * 128 + g];
        }
#pragma unroll
        for (int mf = 0; mf < 4; ++mf)
#pragma unroll
            for (int nf = 0; nf < 2; ++nf) {
                acc2[mf][nf] = __builtin_amdgcn_mfma_f32_16x16x32_bf16(
                    gah[mf], gbh[nf], acc2[mf][nf], 0, 0, 0);
                acc2[mf][nf] = __builtin_amdgcn_mfma_f32_16x16x32_bf16(
                    gal[mf], gbh[nf], acc2[mf][nf], 0, 0, 0);
                acc2[mf][nf] = __builtin_amdgcn_mfma_f32_16x16x32_bf16(
                    gah[mf], gbl[nf], acc2[mf][nf], 0, 0, 0);
            }
    }

    // ---- bias + relu + transpose + frag-layout store, two n-halves of 64
#pragma unroll
    for (int h = 0; h < 2; ++h) {
        __syncthreads();
        if ((wn >> 1) == h) {
#pragma unroll
            for (int mf = 0; mf < 4; ++mf)
#pragma unroll
                for (int nf = 0; nf < 2; ++nf) {
                    int mb = wm * 64 + mf * 16 + lq * 4;
                    int nl = (wn & 1) * 32 + nf * 16 + lr;
#pragma unroll
                    for (int r = 0; r < 4; ++r) {
                        float y = fmaxf(acc2[mf][nf][r] + bv[nf], 0.0f);
                        sT[(mb + r) * 68 + nl] = y;
                    }
                }
        }
        __syncthreads();
        {
            const int m = t >> 2, seg = t & 3;
            const float* rp = &sT[m * 68 + seg * 16];
            ushort hs[16], ls[16];
#pragma unroll
            for (int j = 0; j < 16; ++j) {
                float y = rp[j];
                hs[j] = f2b(y);
                ls[j] = f2b(y - b2f(hs[j]));
            }
            const int wm2 = m >> 6, mf2 = (m >> 4) & 3, lr2 = m & 15;
#pragma unroll
            for (int g = 0; g < 2; ++g) {
                int chl = h * 64 + seg * 16 + g * 8;          // local ch in 128
                int ks = ntile * 4 + (chl >> 5);
                int lq2 = (chl >> 3) & 3;
                size_t o = (((size_t)(b * 2 + wm2) * 4 + mf2) * 16 + ks) * 512
                         + (lq2 * 16 + lr2) * 8;
                *(int4*)&Yfh[o] = *(int4*)&hs[g * 8];
                *(int4*)&Yfl[o] = *(int4*)&ls[g * 8];
            }
        }
    }
}

// ---------------- LayerNorm + transposed write-out (frag-layout input) ----------------
// grid 128 = (wm, b); block 256 = 4 waves (one mf each). out[s=wm][b][c][p]
__global__ __launch_bounds__(256) void ln_out_k(const ushort* __restrict__ xh,
                                                const ushort* __restrict__ xl,
                                                const float* __restrict__ lw,
                                                const float* __restrict__ lb,
                                                float* __restrict__ out) {
    __shared__ float tile[32][68];
    __shared__ float muA[64], invA[64];
    const int t = threadIdx.x, lane = t & 63, mf = t >> 6;
    const int lr = lane & 15, lq = lane >> 4;
    const int b = blockIdx.x & 63, wm = blockIdx.x >> 6;
    const size_t base = ((size_t)(b * 2 + wm) * 4 + mf) * 8192 + lane * 8;

    float s1 = 0.f, s2 = 0.f;
    for (int ks = 0; ks < 16; ++ks) {
        int4 hh = *(const int4*)&xh[base + ks * 512];
        int4 llv = *(const int4*)&xl[base + ks * 512];
        ushort* hp = (ushort*)&hh;
        ushort* lp = (ushort*)&llv;
#pragma unroll
        for (int j = 0; j < 8; ++j) {
            float v = b2f(hp[j]) + b2f(lp[j]);
            s1 += v;
            s2 += v * v;
        }
    }
    s1 += __shfl_xor(s1, 16); s2 += __shfl_xor(s2, 16);
    s1 += __shfl_xor(s1, 32); s2 += __shfl_xor(s2, 32);
    if (lq == 0) {
        float mu = s1 * (1.0f / C_);
        muA[mf * 16 + lr] = mu;
        invA[mf * 16 + lr] = rsqrtf(s2 * (1.0f / C_) - mu * mu + EPS_);
    }
    __syncthreads();

    const int p = mf * 16 + lr;
    const float mu = muA[p], inv = invA[p];
    const size_t ob = (size_t)wm * (B_ * C_ * 64) + (size_t)b * (C_ * 64);

    for (int ks = 0; ks < 16; ++ks) {
        {
            int4 hh = *(const int4*)&xh[base + ks * 512];
            int4 llv = *(const int4*)&xl[base + ks * 512];
            ushort* hp = (ushort*)&hh;
            ushort* lp = (ushort*)&llv;
            int c = ks * 32 + lq * 8;
            float4 w0 = *(const float4*)&lw[c];
            float4 w1 = *(const float4*)&lw[c + 4];
            float4 b0 = *(const float4*)&lb[c];
            float4 b1 = *(const float4*)&lb[c + 4];
            float wv_[8] = {w0.x, w0.y, w0.z, w0.w, w1.x, w1.y, w1.z, w1.w};
            float bb_[8] = {b0.x, b0.y, b0.z, b0.w, b1.x, b1.y, b1.z, b1.w};
#pragma unroll
            for (int j = 0; j < 8; ++j) {
                float v = b2f(hp[j]) + b2f(lp[j]);
                tile[lq * 8 + j][p] = (v - mu) * inv * wv_[j] + bb_[j];
            }
        }
        __syncthreads();
        {
            int ch = t >> 3, p0 = (t & 7) * 8;
            float4 v0 = *(const float4*)&tile[ch][p0];
            float4 v1 = *(const float4*)&tile[ch][p0 + 4];
            *(float4*)&out[ob + (size_t)(ks * 32 + ch) * 64 + p0] = v0;
            *(float4*)&out[ob + (size_t)(ks * 32 + ch) * 64 + p0 + 4] = v1;
        }
        __syncthreads();
    }
}

// ---------------- launch ----------------

extern "C" void kernel_launch(void* const* d_in, const int* in_sizes, int n_in,
                              void* d_out, int out_size, void* d_ws, size_t ws_size,
                              hipStream_t stream) {
    const float* rgb = (const float*)d_in[0];
    const float* ir  = (const float*)d_in[1];
    const int*   ei  = (const int*)d_in[2];
    const float* pos = (const float*)d_in[3];
    const float* Wg  = (const float*)d_in[4];
    const float* bg  = (const float*)d_in[5];
    const float* lw  = (const float*)d_in[6];
    const float* lb  = (const float*)d_in[7];
    float* out = (float*)d_out;

    char* ws = (char*)d_ws;
    ushort* x0h  = (ushort*)(ws);
    ushort* x0l  = (ushort*)(ws + 8388608);
    ushort* x1h  = (ushort*)(ws + 16777216);
    ushort* x1l  = (ushort*)(ws + 25165824);
    ushort* Wfh  = (ushort*)(ws + 33554432);
    ushort* Wfl  = (ushort*)(ws + 37748736);
    float*  Afp  = (float*)(ws + 41943040);
    float*  deg  = Afp + NNODE * NNODE;
    ushort* Afh  = (ushort*)(ws + 42009088);
    ushort* Afl  = (ushort*)(ws + 42041856);

    zero_k<<<(NNODE * NNODE + NNODE + 255) / 256, 256, 0, stream>>>(Afp, NNODE * NNODE + NNODE);
    count_deg_k<<<(NEDGE + 255) / 256, 256, 0, stream>>>(ei, deg);
    dinv_k<<<1, NNODE, 0, stream>>>(deg);
    build_A_k<<<(NEDGE + NNODE + 255) / 256, 256, 0, stream>>>(ei, deg, Afp);
    splitAfrag_k<<<8, 256, 0, stream>>>(Afp, Afh, Afl);

    wprep_k<<<dim3(8, 8, NLAYERS), 256, 0, stream>>>(Wg, Wfh, Wfl);
    pool_x_k<<<dim3(16, B_), 256, 0, stream>>>(rgb, ir, pos, x0h, x0l);

    for (int l = 0; l < NLAYERS; ++l) {
        const ushort* inh = (l & 1) ? x1h : x0h;
        const ushort* inl = (l & 1) ? x1l : x0l;
        ushort* outh = (l & 1) ? x0h : x1h;
        ushort* outl = (l & 1) ? x0l : x1l;
        gemm_fused_k<<<dim3(4, B_), 512, 0, stream>>>(
            inh, inl, Wfh + (size_t)l * C_ * C_, Wfl + (size_t)l * C_ * C_,
            Afh, Afl, bg + (size_t)l * C_, outh, outl);
    }

    ln_out_k<<<2 * B_, 256, 0, stream>>>(x0h, x0l, lw, lb, out);
}

// Round 8
// 300.056 us; speedup vs baseline: 1.5510x; 1.0043x over previous
//
#include <hip/hip_runtime.h>

#define B_      64
#define C_      512
#define NNODE   128
#define NEDGE   1024
#define NLAYERS 8
#define EPS_    1e-5f

typedef __attribute__((ext_vector_type(8))) short bf16x8;
typedef __attribute__((ext_vector_type(4))) float f32x4;

__device__ __forceinline__ ushort f2b(float x) {
    unsigned u = __builtin_bit_cast(unsigned, x);
    unsigned r = (u + 0x7fffu + ((u >> 16) & 1u)) >> 16;
    return (ushort)r;
}
__device__ __forceinline__ float b2f(ushort h) {
    unsigned u = ((unsigned)h) << 16;
    return __builtin_bit_cast(float, u);
}

// Fragment layout for a [rows][512] bf16 matrix consumed as MFMA A/B operand:
//   frag[rowblk][mf][ks][lane][8]   lane=(lq<<4)|lr
//   element (row = base + mf*16 + lr, k = ks*32 + lq*8 + j)
// Every wave fragment load = base + lane*16B -> one coalesced 1KB transaction.

// ---------------- graph prep ----------------

__global__ void zero_k(float* __restrict__ p, int n) {
    int i = blockIdx.x * 256 + threadIdx.x;
    if (i < n) p[i] = 0.0f;
}

__global__ void count_deg_k(const int* __restrict__ ei, float* __restrict__ deg) {
    int e = blockIdx.x * 256 + threadIdx.x;
    if (e < NEDGE) atomicAdd(&deg[ei[NEDGE + e]], 1.0f);
}

__global__ void dinv_k(float* __restrict__ deg) {
    int n = threadIdx.x;
    deg[n] = 1.0f / sqrtf(deg[n] + 1.0f);
}

__global__ void build_A_k(const int* __restrict__ ei, const float* __restrict__ dinv,
                          float* __restrict__ A) {
    int e = blockIdx.x * 256 + threadIdx.x;
    if (e < NEDGE) {
        int s = ei[e];
        int d = ei[NEDGE + e];
        atomicAdd(&A[d * NNODE + s], dinv[s] * dinv[d]);
    } else if (e < NEDGE + NNODE) {
        int n = e - NEDGE;
        atomicAdd(&A[n * NNODE + n], dinv[n] * dinv[n]);
    }
}

// A(128x128 fp32) -> frag layout [wm2][mf4][kk4][lane64][8], split h/l
__global__ void splitAfrag_k(const float* __restrict__ A, ushort* __restrict__ Ah,
                             ushort* __restrict__ Al) {
    int gid = blockIdx.x * 256 + threadIdx.x;   // 0..2047
    if (gid >= 2048) return;
    int lane = gid & 63, lr = lane & 15, lq = lane >> 4;
    int kk = (gid >> 6) & 3, mf = (gid >> 8) & 3, wm = (gid >> 10) & 1;
    int row = wm * 64 + mf * 16 + lr;
    int k = kk * 32 + lq * 8;
    ushort hh[8], ll[8];
#pragma unroll
    for (int j = 0; j < 8; ++j) {
        float v = A[row * NNODE + k + j];
        hh[j] = f2b(v);
        ll[j] = f2b(v - b2f(hh[j]));
    }
    *(int4*)&Ah[(size_t)gid * 8] = *(int4*)hh;
    *(int4*)&Al[(size_t)gid * 8] = *(int4*)ll;
}

// ---------------- W -> frag layout + split ----------------
// Wf[l][ntile4][wn4][nf2][ks16][lane64][8], element (n,k)=W[k][n]
__global__ __launch_bounds__(256) void wprep_k(const float* __restrict__ W,
                                               ushort* __restrict__ Wfh,
                                               ushort* __restrict__ Wfl) {
    __shared__ float tl[64][68];
    const int t = threadIdx.x;
    const int n0 = blockIdx.x * 64, k0 = blockIdx.y * 64, l = blockIdx.z;
    const float* Wl = W + (size_t)l * C_ * C_;
    {
        int kk = t >> 2, nc = (t & 3) * 16;
        const float* src = Wl + (size_t)(k0 + kk) * C_ + n0 + nc;
#pragma unroll
        for (int g = 0; g < 4; ++g)
            *(float4*)&tl[kk][nc + g * 4] = *(const float4*)(src + g * 4);
    }
    __syncthreads();
    {
        int nn = t >> 2, kc = (t & 3) * 16;
        int n = n0 + nn;
        int ntile = n >> 7, wn = (n >> 5) & 3, nf = (n >> 4) & 1, lr = n & 15;
        ushort h[16], lo[16];
#pragma unroll
        for (int j = 0; j < 16; ++j) {
            float v = tl[kc + j][nn];
            h[j] = f2b(v);
            lo[j] = f2b(v - b2f(h[j]));
        }
#pragma unroll
        for (int g = 0; g < 2; ++g) {
            int kb = k0 + kc + g * 8;
            int ks = kb >> 5, lq = (kb >> 3) & 3;
            size_t o = (((((size_t)l * 4 + ntile) * 4 + wn) * 2 + nf) * 16 + ks) * 512
                     + (lq * 16 + lr) * 8;
            *(int4*)&Wfh[o] = *(int4*)&h[g * 8];
            *(int4*)&Wfl[o] = *(int4*)&lo[g * 8];
        }
    }
}

// ---------------- fused pool + pos + split -> x0 (frag layout) ----------------
// 32 channels/block, grid (16, 64). nontemporal streaming loads.
__global__ __launch_bounds__(256) void pool_x_k(const float* __restrict__ rgb,
                                                const float* __restrict__ ir,
                                                const float* __restrict__ pos,
                                                ushort* __restrict__ xh,
                                                ushort* __restrict__ xl) {
    __shared__ float lds[32][130];
    const int t = threadIdx.x, l = t & 63, wv = t >> 6;
    const int c0 = blockIdx.x * 32, b = blockIdx.y;

    for (int i = 0; i < 16; ++i) {
        int p = wv * 16 + i;
        int src = p >> 5, cc = p & 31;
        const float* base = (src ? ir : rgb) + ((size_t)(b * C_ + c0 + cc)) * 1024 + l * 4;
        float s[4];
#pragma unroll
        for (int g = 0; g < 4; ++g) {
            f32x4 v = __builtin_nontemporal_load((const f32x4*)(base + g * 256));
            s[g] = v.x + v.y + v.z + v.w;
        }
#pragma unroll
        for (int g = 0; g < 4; ++g) {
            s[g] += __shfl_xor(s[g], 8);
            s[g] += __shfl_xor(s[g], 16);
        }
        if (((l >> 3) & 3) == 0) {
            int ha = l & 7, hi = l >> 5;
#pragma unroll
            for (int g = 0; g < 4; ++g)
                lds[cc][src * 64 + (2 * g + hi) * 8 + ha] = s[g] * 0.0625f;
        }
    }
    __syncthreads();

    const int n = t >> 1, cb = (t & 1) * 16;
    float v[16];
#pragma unroll
    for (int j = 0; j < 16; j += 4) {
        float4 pv = *(const float4*)&pos[(size_t)n * C_ + c0 + cb + j];
        v[j + 0] = lds[cb + j + 0][n] + pv.x;
        v[j + 1] = lds[cb + j + 1][n] + pv.y;
        v[j + 2] = lds[cb + j + 2][n] + pv.z;
        v[j + 3] = lds[cb + j + 3][n] + pv.w;
    }
    ushort hs[16], ls[16];
#pragma unroll
    for (int j = 0; j < 16; ++j) {
        hs[j] = f2b(v[j]);
        ls[j] = f2b(v[j] - b2f(hs[j]));
    }
    // frag-layout stores: granule = 8 channels
    const int wm = n >> 6, mf = (n >> 4) & 3, lr = n & 15;
    const int ks = blockIdx.x;   // c0 = 32*bx -> ks = bx
#pragma unroll
    for (int g = 0; g < 2; ++g) {
        int lq = ((cb + g * 8) >> 3) & 3;
        size_t o = (((size_t)(b * 2 + wm) * 4 + mf) * 16 + ks) * 512 + (lq * 16 + lr) * 8;
        *(int4*)&xh[o] = *(int4*)&hs[g * 8];
        *(int4*)&xl[o] = *(int4*)&ls[g * 8];
    }
}

// ---------------- fused layer: x' = relu(A @ (x @ W) + bias) ----------------
// flat grid 256, XCD-aware decode: 4 ntile-siblings of a batch share one XCD's L2.
// 512 thr = 8 waves (2m x 4n), wave tile 64x32. Stage-1 frag-direct, no barriers.
__global__ __launch_bounds__(512, 2) void gemm_fused_k(
    const ushort* __restrict__ Xfh, const ushort* __restrict__ Xfl,
    const ushort* __restrict__ Wfh, const ushort* __restrict__ Wfl,
    const ushort* __restrict__ Afh, const ushort* __restrict__ Afl,
    const float* __restrict__ bias,
    ushort* __restrict__ Yfh, ushort* __restrict__ Yfl) {
    __shared__ __align__(16) char smem[65536];
    ushort* sPh = (ushort*)smem;                 // [128 n][128 m] granule-swizzled
    ushort* sPl = (ushort*)(smem + 32768);
    float*  sT  = (float*)smem;                  // [128][68] half-tile

    const int t = threadIdx.x, lane = t & 63;
    const int wv = t >> 6, wm = wv >> 2, wn = wv & 3;
    const int lr = lane & 15, lq = lane >> 4;
    // XCD-aware: bid%8 = XCD. Give each XCD 8 batches x 4 ntiles.
    const int bid = blockIdx.x;
    const int xcd = bid & 7, slot = bid >> 3;
    const int b = xcd * 8 + (slot >> 2);
    const int ntile = slot & 3;
    const int bn = ntile * 128;

    // stage-1 fragment bases (ushort indices); ks stride 512, mf/nf stride 8192
    const size_t xb = ((size_t)(b * 2 + wm) * 4) * 8192 + lane * 8;
    const size_t wb = ((size_t)(ntile * 4 + wn) * 2) * 8192 + lane * 8;

    f32x4 acc[4][2];
#pragma unroll
    for (int i = 0; i < 4; ++i)
#pragma unroll
        for (int j = 0; j < 2; ++j) acc[i][j] = (f32x4){0.f, 0.f, 0.f, 0.f};

    float bv[2];
#pragma unroll
    for (int nf = 0; nf < 2; ++nf) bv[nf] = bias[bn + wn * 32 + nf * 16 + lr];

#pragma unroll 2
    for (int ks = 0; ks < 16; ++ks) {
        bf16x8 fah[4], fal[4], fbh[2], fbl[2];
#pragma unroll
        for (int mf = 0; mf < 4; ++mf) {
            fah[mf] = *(const bf16x8*)&Xfh[xb + mf * 8192 + ks * 512];
            fal[mf] = *(const bf16x8*)&Xfl[xb + mf * 8192 + ks * 512];
        }
#pragma unroll
        for (int nf = 0; nf < 2; ++nf) {
            fbh[nf] = *(const bf16x8*)&Wfh[wb + nf * 8192 + ks * 512];
            fbl[nf] = *(const bf16x8*)&Wfl[wb + nf * 8192 + ks * 512];
        }
#pragma unroll
        for (int mf = 0; mf < 4; ++mf)
#pragma unroll
            for (int nf = 0; nf < 2; ++nf) {
                acc[mf][nf] = __builtin_amdgcn_mfma_f32_16x16x32_bf16(
                    fah[mf], fbh[nf], acc[mf][nf], 0, 0, 0);
                acc[mf][nf] = __builtin_amdgcn_mfma_f32_16x16x32_bf16(
                    fal[mf], fbh[nf], acc[mf][nf], 0, 0, 0);
                acc[mf][nf] = __builtin_amdgcn_mfma_f32_16x16x32_bf16(
                    fah[mf], fbl[nf], acc[mf][nf], 0, 0, 0);
            }
    }

    // ---- XW tile -> sP[n][m] swizzled bf16-pair (transpose for stage-2 B operand)
#pragma unroll
    for (int mf = 0; mf < 4; ++mf) {
        int gm = wm * 8 + mf * 2 + (lq >> 1);
        int moff = (lq & 1) * 4;
#pragma unroll
        for (int nf = 0; nf < 2; ++nf) {
            int n = wn * 32 + nf * 16 + lr;
            int addr = n * 128 + ((gm ^ (n & 15)) << 3) + moff;
            ushort4 hu, lu;
            float y0 = acc[mf][nf][0], y1 = acc[mf][nf][1];
            float y2 = acc[mf][nf][2], y3 = acc[mf][nf][3];
            hu.x = f2b(y0); lu.x = f2b(y0 - b2f(hu.x));
            hu.y = f2b(y1); lu.y = f2b(y1 - b2f(hu.y));
            hu.z = f2b(y2); lu.z = f2b(y2 - b2f(hu.z));
            hu.w = f2b(y3); lu.w = f2b(y3 - b2f(hu.w));
            *(ushort4*)&sPh[addr] = hu;
            *(ushort4*)&sPl[addr] = lu;
        }
    }
    __syncthreads();

    // ---- stage 2: acc2 = A(128x128) @ XW(tile); A frags coalesced from L2
    f32x4 acc2[4][2];
#pragma unroll
    for (int i = 0; i < 4; ++i)
#pragma unroll
        for (int j = 0; j < 2; ++j) acc2[i][j] = (f32x4){0.f, 0.f, 0.f, 0.f};

#pragma unroll
    for (int kk = 0; kk < 4; ++kk) {
        bf16x8 gah[4], gal[4], gbh[2], gbl[2];
#pragma unroll
        for (int mf = 0; mf < 4; ++mf) {
            size_t o = (size_t)((wm * 4 + mf) * 4 + kk) * 512 + lane * 8;
            gah[mf] = *(const bf16x8*)&Afh[o];
            gal[mf] = *(const bf16x8*)&Afl[o];
        }
#pragma unroll
        for (int nf = 0; nf < 2; ++nf) {
            int n = wn * 32 + nf * 16 + lr;
            int g = (((kk * 4 + lq) ^ (n & 15)) << 3);
            gbh[nf] = *(const bf16x8*)&sPh[n * 128 + g];
            gbl[nf] = *(const bf16x8*)&sPl[n * 128 + g];
        }
#pragma unroll
        for (int mf = 0; mf < 4; ++mf)
#pragma unroll
            for (int nf = 0; nf < 2; ++nf) {
                acc2[mf][nf] = __builtin_amdgcn_mfma_f32_16x16x32_bf16(
                    gah[mf], gbh[nf], acc2[mf][nf], 0, 0, 0);
                acc2[mf][nf] = __builtin_amdgcn_mfma_f32_16x16x32_bf16(
                    gal[mf], gbh[nf], acc2[mf][nf], 0, 0, 0);
                acc2[mf][nf] = __builtin_amdgcn_mfma_f32_16x16x32_bf16(
                    gah[mf], gbl[nf], acc2[mf][nf], 0, 0, 0);
            }
    }

    // ---- bias + relu + transpose + frag-layout store, two n-halves of 64
#pragma unroll
    for (int h = 0; h < 2; ++h) {
        __syncthreads();
        if ((wn >> 1) == h) {
#pragma unroll
            for (int mf = 0; mf < 4; ++mf)
#pragma unroll
                for (int nf = 0; nf < 2; ++nf) {
                    int mb = wm * 64 + mf * 16 + lq * 4;
                    int nl = (wn & 1) * 32 + nf * 16 + lr;
#pragma unroll
                    for (int r = 0; r < 4; ++r) {
                        float y = fmaxf(acc2[mf][nf][r] + bv[nf], 0.0f);
                        sT[(mb + r) * 68 + nl] = y;
                    }
                }
        }
        __syncthreads();
        {
            const int m = t >> 2, seg = t & 3;
            const float* rp = &sT[m * 68 + seg * 16];
            ushort hs[16], ls[16];
#pragma unroll
            for (int j = 0; j < 16; ++j) {
                float y = rp[j];
                hs[j] = f2b(y);
                ls[j] = f2b(y - b2f(hs[j]));
            }
            const int wm2 = m >> 6, mf2 = (m >> 4) & 3, lr2 = m & 15;
#pragma unroll
            for (int g = 0; g < 2; ++g) {
                int chl = h * 64 + seg * 16 + g * 8;          // local ch in 128
                int ks = ntile * 4 + (chl >> 5);
                int lq2 = (chl >> 3) & 3;
                size_t o = (((size_t)(b * 2 + wm2) * 4 + mf2) * 16 + ks) * 512
                         + (lq2 * 16 + lr2) * 8;
                *(int4*)&Yfh[o] = *(int4*)&hs[g * 8];
                *(int4*)&Yfl[o] = *(int4*)&ls[g * 8];
            }
        }
    }
}

// ---------------- LayerNorm + transposed write-out (frag-layout input) ----------------
// grid 128 = (wm, b); block 256 = 4 waves (one mf each). out[s=wm][b][c][p]
__global__ __launch_bounds__(256) void ln_out_k(const ushort* __restrict__ xh,
                                                const ushort* __restrict__ xl,
                                                const float* __restrict__ lw,
                                                const float* __restrict__ lb,
                                                float* __restrict__ out) {
    __shared__ float tile[32][68];
    __shared__ float muA[64], invA[64];
    const int t = threadIdx.x, lane = t & 63, mf = t >> 6;
    const int lr = lane & 15, lq = lane >> 4;
    const int b = blockIdx.x & 63, wm = blockIdx.x >> 6;
    const size_t base = ((size_t)(b * 2 + wm) * 4 + mf) * 8192 + lane * 8;

    float s1 = 0.f, s2 = 0.f;
    for (int ks = 0; ks < 16; ++ks) {
        int4 hh = *(const int4*)&xh[base + ks * 512];
        int4 llv = *(const int4*)&xl[base + ks * 512];
        ushort* hp = (ushort*)&hh;
        ushort* lp = (ushort*)&llv;
#pragma unroll
        for (int j = 0; j < 8; ++j) {
            float v = b2f(hp[j]) + b2f(lp[j]);
            s1 += v;
            s2 += v * v;
        }
    }
    s1 += __shfl_xor(s1, 16); s2 += __shfl_xor(s2, 16);
    s1 += __shfl_xor(s1, 32); s2 += __shfl_xor(s2, 32);
    if (lq == 0) {
        float mu = s1 * (1.0f / C_);
        muA[mf * 16 + lr] = mu;
        invA[mf * 16 + lr] = rsqrtf(s2 * (1.0f / C_) - mu * mu + EPS_);
    }
    __syncthreads();

    const int p = mf * 16 + lr;
    const float mu = muA[p], inv = invA[p];
    const size_t ob = (size_t)wm * (B_ * C_ * 64) + (size_t)b * (C_ * 64);

    for (int ks = 0; ks < 16; ++ks) {
        {
            int4 hh = *(const int4*)&xh[base + ks * 512];
            int4 llv = *(const int4*)&xl[base + ks * 512];
            ushort* hp = (ushort*)&hh;
            ushort* lp = (ushort*)&llv;
            int c = ks * 32 + lq * 8;
            float4 w0 = *(const float4*)&lw[c];
            float4 w1 = *(const float4*)&lw[c + 4];
            float4 b0 = *(const float4*)&lb[c];
            float4 b1 = *(const float4*)&lb[c + 4];
            float wv_[8] = {w0.x, w0.y, w0.z, w0.w, w1.x, w1.y, w1.z, w1.w};
            float bb_[8] = {b0.x, b0.y, b0.z, b0.w, b1.x, b1.y, b1.z, b1.w};
#pragma unroll
            for (int j = 0; j < 8; ++j) {
                float v = b2f(hp[j]) + b2f(lp[j]);
                tile[lq * 8 + j][p] = (v - mu) * inv * wv_[j] + bb_[j];
            }
        }
        __syncthreads();
        {
            int ch = t >> 3, p0 = (t & 7) * 8;
            float4 v0 = *(const float4*)&tile[ch][p0];
            float4 v1 = *(const float4*)&tile[ch][p0 + 4];
            *(float4*)&out[ob + (size_t)(ks * 32 + ch) * 64 + p0] = v0;
            *(float4*)&out[ob + (size_t)(ks * 32 + ch) * 64 + p0 + 4] = v1;
        }
        __syncthreads();
    }
}

// ---------------- launch ----------------

extern "C" void kernel_launch(void* const* d_in, const int* in_sizes, int n_in,
                              void* d_out, int out_size, void* d_ws, size_t ws_size,
                              hipStream_t stream) {
    const float* rgb = (const float*)d_in[0];
    const float* ir  = (const float*)d_in[1];
    const int*   ei  = (const int*)d_in[2];
    const float* pos = (const float*)d_in[3];
    const float* Wg  = (const float*)d_in[4];
    const float* bg  = (const float*)d_in[5];
    const float* lw  = (const float*)d_in[6];
    const float* lb  = (const float*)d_in[7];
    float* out = (float*)d_out;

    char* ws = (char*)d_ws;
    ushort* x0h  = (ushort*)(ws);
    ushort* x0l  = (ushort*)(ws + 8388608);
    ushort* x1h  = (ushort*)(ws + 16777216);
    ushort* x1l  = (ushort*)(ws + 25165824);
    ushort* Wfh  = (ushort*)(ws + 33554432);
    ushort* Wfl  = (ushort*)(ws + 37748736);
    float*  Afp  = (float*)(ws + 41943040);
    float*  deg  = Afp + NNODE * NNODE;
    ushort* Afh  = (ushort*)(ws + 42009088);
    ushort* Afl  = (ushort*)(ws + 42041856);

    zero_k<<<(NNODE * NNODE + NNODE + 255) / 256, 256, 0, stream>>>(Afp, NNODE * NNODE + NNODE);
    count_deg_k<<<(NEDGE + 255) / 256, 256, 0, stream>>>(ei, deg);
    dinv_k<<<1, NNODE, 0, stream>>>(deg);
    build_A_k<<<(NEDGE + NNODE + 255) / 256, 256, 0, stream>>>(ei, deg, Afp);
    splitAfrag_k<<<8, 256, 0, stream>>>(Afp, Afh, Afl);

    wprep_k<<<dim3(8, 8, NLAYERS), 256, 0, stream>>>(Wg, Wfh, Wfl);
    pool_x_k<<<dim3(16, B_), 256, 0, stream>>>(rgb, ir, pos, x0h, x0l);

    for (int l = 0; l < NLAYERS; ++l) {
        const ushort* inh = (l & 1) ? x1h : x0h;
        const ushort* inl = (l & 1) ? x1l : x0l;
        ushort* outh = (l & 1) ? x0h : x1h;
        ushort* outl = (l & 1) ? x0l : x1l;
        gemm_fused_k<<<256, 512, 0, stream>>>(
            inh, inl, Wfh + (size_t)l * C_ * C_, Wfl + (size_t)l * C_ * C_,
            Afh, Afl, bg + (size_t)l * C_, outh, outl);
    }

    ln_out_k<<<2 * B_, 256, 0, stream>>>(x0h, x0l, lw, lb, out);
}